// Round 3
// baseline (1591.329 us; speedup 1.0000x reference)
//
#include <hip/hip_runtime.h>

#define IN_CH 500
#define KSTEPS 10

typedef unsigned int u32;
typedef unsigned short u16;

__device__ __forceinline__ float bf2f(u16 u) {
    union { u32 i; float f; } v; v.i = ((u32)u) << 16; return v.f;
}
__device__ __forceinline__ u16 f2bf(float f) {
    union { float f; u32 i; } v; v.f = f;
    u32 x = v.i;
    return (u16)((x + 0x7FFFu + ((x >> 16) & 1u)) >> 16);  // RNE
}

// ---------------- runtime dtype detection ----------------
// flags[0] = 1 if float tensors are f32 storage (else bf16)
// flags[1] = 1 if edge_index is int64 storage (else int32)
__global__ void detect_kernel(const u16* __restrict__ w1raw,
                              const int* __restrict__ ei,
                              u32* __restrict__ flags) {
    int t = threadIdx.x;  // 64 threads
    // probe W1 interpreted as bf16: real bf16 W1 has |v| <= ~0.05;
    // f32 storage -> low u16s are random mantissa bits -> huge values
    float m = fabsf(bf2f(w1raw[t]));
    m = fmaxf(m, fabsf(bf2f(w1raw[64 + t])));
    m = fmaxf(m, fabsf(bf2f(w1raw[128 + t])));
    for (int off = 32; off; off >>= 1) m = fmaxf(m, __shfl_down(m, off));
    // probe edge_index: int64 little-endian -> all odd int32 words are 0
    u32 o = (u32)ei[2 * t + 1];
    o |= (u32)ei[2 * t + 129];
    for (int off = 32; off; off >>= 1) o |= __shfl_down(o, off);
    if (t == 0) {
        flags[0] = (m > 10.0f) ? 1u : 0u;
        flags[1] = (o == 0u) ? 1u : 0u;
    }
}

// ---------------- MLP: h0 = relu(x@W1+b1)@W2+b2, f32 out ----------------
// 64 nodes x 64 hid per block, 256 threads, 4x4 acc/thread, K chunked by 32.
__global__ __launch_bounds__(256) void mlp_kernel(
    const void* __restrict__ xv, const void* __restrict__ W1v,
    const void* __restrict__ b1v, const void* __restrict__ W2v,
    const void* __restrict__ b2v, float* __restrict__ h0,
    const u32* __restrict__ flags, int N)
{
    __shared__ float xs[32][64];    // [k][node]
    __shared__ float ws1[32][64];   // [k][hid]
    __shared__ float hh[64][65];    // [node][hid], +1 pad
    __shared__ float w2s[64][16];
    __shared__ float b1s[64];
    __shared__ float b2s[16];

    const int isF32 = (int)flags[0];
    const float* xf  = (const float*)xv;  const u16* xh  = (const u16*)xv;
    const float* W1f = (const float*)W1v; const u16* W1h = (const u16*)W1v;
    const float* b1f = (const float*)b1v; const u16* b1h = (const u16*)b1v;
    const float* W2f = (const float*)W2v; const u16* W2h = (const u16*)W2v;
    const float* b2f = (const float*)b2v; const u16* b2h = (const u16*)b2v;

    const int t = threadIdx.x;
    const int tx = t & 15;          // hid quad: tx*4
    const int ty = t >> 4;          // node quad: ty*4
    const int nodeBase = blockIdx.x * 64;

    for (int i = t; i < 1024; i += 256)
        w2s[i >> 4][i & 15] = isF32 ? W2f[i] : bf2f(W2h[i]);
    if (t < 64) b1s[t] = isF32 ? b1f[t] : bf2f(b1h[t]);
    if (t < 16) b2s[t] = isF32 ? b2f[t] : bf2f(b2h[t]);

    float acc[4][4];
#pragma unroll
    for (int r = 0; r < 4; ++r)
#pragma unroll
        for (int c = 0; c < 4; ++c) acc[r][c] = 0.f;

    for (int k0 = 0; k0 < 512; k0 += 32) {   // K padded 500->512 with zeros
        __syncthreads();
        // stage x tile: 64 nodes x 32 k
#pragma unroll
        for (int rr = 0; rr < 2; ++rr) {
            int r = t + rr * 256;
            int n = r >> 3, q = r & 7;
            int k = k0 + q * 4;
            int gn = nodeBase + n;
            float f0 = 0.f, f1 = 0.f, f2 = 0.f, f3 = 0.f;
            if (gn < N && k + 3 < IN_CH) {
                if (isF32) {
                    float4 v = *(const float4*)(xf + (size_t)gn * IN_CH + k);
                    f0 = v.x; f1 = v.y; f2 = v.z; f3 = v.w;
                } else {
                    ushort4 v = *(const ushort4*)(xh + (size_t)gn * IN_CH + k);
                    f0 = bf2f(v.x); f1 = bf2f(v.y); f2 = bf2f(v.z); f3 = bf2f(v.w);
                }
            }
            xs[q * 4 + 0][n] = f0; xs[q * 4 + 1][n] = f1;
            xs[q * 4 + 2][n] = f2; xs[q * 4 + 3][n] = f3;
        }
        // stage W1 tile: 32 k x 64 hid
#pragma unroll
        for (int rr = 0; rr < 2; ++rr) {
            int r = t + rr * 256;
            int krow = r >> 4, cq = r & 15;
            int k = k0 + krow;
            float f0 = 0.f, f1 = 0.f, f2 = 0.f, f3 = 0.f;
            if (k < IN_CH) {
                if (isF32) {
                    float4 v = *(const float4*)(W1f + (size_t)k * 64 + cq * 4);
                    f0 = v.x; f1 = v.y; f2 = v.z; f3 = v.w;
                } else {
                    ushort4 v = *(const ushort4*)(W1h + (size_t)k * 64 + cq * 4);
                    f0 = bf2f(v.x); f1 = bf2f(v.y); f2 = bf2f(v.z); f3 = bf2f(v.w);
                }
            }
            ws1[krow][cq * 4 + 0] = f0; ws1[krow][cq * 4 + 1] = f1;
            ws1[krow][cq * 4 + 2] = f2; ws1[krow][cq * 4 + 3] = f3;
        }
        __syncthreads();
#pragma unroll
        for (int kk = 0; kk < 32; ++kk) {
            const float4 a = *(const float4*)&xs[kk][ty * 4];
            const float4 b = *(const float4*)&ws1[kk][tx * 4];
            float av[4] = {a.x, a.y, a.z, a.w};
            float bv[4] = {b.x, b.y, b.z, b.w};
#pragma unroll
            for (int r = 0; r < 4; ++r)
#pragma unroll
                for (int c = 0; c < 4; ++c) acc[r][c] += av[r] * bv[c];
        }
    }
#pragma unroll
    for (int r = 0; r < 4; ++r)
#pragma unroll
        for (int c = 0; c < 4; ++c) {
            float v = acc[r][c] + b1s[tx * 4 + c];
            hh[ty * 4 + r][tx * 4 + c] = v > 0.f ? v : 0.f;
        }
    __syncthreads();
    {
        int n = t >> 2;
        int o4 = (t & 3) * 4;
        float o0 = b2s[o4], o1 = b2s[o4 + 1], o2 = b2s[o4 + 2], o3 = b2s[o4 + 3];
#pragma unroll
        for (int j = 0; j < 64; ++j) {
            float hv = hh[n][j];
            o0 += hv * w2s[j][o4];     o1 += hv * w2s[j][o4 + 1];
            o2 += hv * w2s[j][o4 + 2]; o3 += hv * w2s[j][o4 + 3];
        }
        int gn = nodeBase + n;
        if (gn < N) {
            float4 o = {o0, o1, o2, o3};
            *(float4*)(h0 + (size_t)gn * 16 + o4) = o;
        }
    }
}

// ---------------- graph preprocessing ----------------
__global__ void zero_u32(u32* __restrict__ p, int n) {
    int i = blockIdx.x * 256 + threadIdx.x;
    if (i < n) p[i] = 0u;
}

__device__ __forceinline__ int ei_src(const int* ei, int E, int e, int i64) {
    return i64 ? ei[2 * e] : ei[e];
}
__device__ __forceinline__ int ei_dst(const int* ei, int E, int e, int i64) {
    return i64 ? ei[2 * (E + e)] : ei[E + e];
}

__global__ void deg_kernel(const int* __restrict__ ei, int E, u32* __restrict__ cnt,
                           const u32* __restrict__ flags) {
    int e = blockIdx.x * 256 + threadIdx.x;
    int i64 = (int)flags[1];
    if (e < E) atomicAdd(&cnt[ei_dst(ei, E, e, i64)], 1u);
}

__global__ void dinv_kernel(const u32* __restrict__ cnt, float* __restrict__ dinv, int N) {
    int i = blockIdx.x * 256 + threadIdx.x;
    if (i < N) {
        float d = (float)(cnt[i] + 1u);      // +1 self-loop
        dinv[i] = rsqrtf(d);
    }
}

__global__ __launch_bounds__(256) void scan1(const u32* __restrict__ cnt,
                                             u32* __restrict__ part, int N) {
    __shared__ u32 s[256];
    int i = blockIdx.x * 256 + threadIdx.x;
    s[threadIdx.x] = (i < N) ? cnt[i] : 0u;
    __syncthreads();
    for (int off = 128; off > 0; off >>= 1) {
        if (threadIdx.x < off) s[threadIdx.x] += s[threadIdx.x + off];
        __syncthreads();
    }
    if (threadIdx.x == 0) part[blockIdx.x] = s[0];
}

__global__ __launch_bounds__(512) void scan2(u32* __restrict__ part,
                                             u32* __restrict__ rowptr, int NB, int N) {
    __shared__ u32 s[512];
    int t = threadIdx.x;
    u32 v = (t < NB) ? part[t] : 0u;
    s[t] = v;
    __syncthreads();
    for (int off = 1; off < 512; off <<= 1) {
        u32 xv = (t >= off) ? s[t - off] : 0u;
        __syncthreads();
        s[t] += xv;
        __syncthreads();
    }
    if (t < NB) part[t] = s[t] - v;          // exclusive block offsets
    if (t == 511) rowptr[N] = s[511];        // total = E
}

__global__ __launch_bounds__(256) void scan3(const u32* __restrict__ cnt,
                                             const u32* __restrict__ part,
                                             u32* __restrict__ rowptr, int N) {
    __shared__ u32 s[256];
    int t = threadIdx.x;
    int i = blockIdx.x * 256 + t;
    u32 v = (i < N) ? cnt[i] : 0u;
    s[t] = v;
    __syncthreads();
    for (int off = 1; off < 256; off <<= 1) {
        u32 xv = (t >= off) ? s[t - off] : 0u;
        __syncthreads();
        s[t] += xv;
        __syncthreads();
    }
    if (i < N) rowptr[i] = part[blockIdx.x] + s[t] - v;
}

// CSR by target; payload = source index only (weights folded into dinv scaling)
__global__ void fill_kernel(const int* __restrict__ ei, int E,
                            const u32* __restrict__ rowptr, u32* __restrict__ fillc,
                            u32* __restrict__ ent, const u32* __restrict__ flags) {
    int e = blockIdx.x * 256 + threadIdx.x;
    int i64 = (int)flags[1];
    if (e < E) {
        int r = ei_src(ei, E, e, i64), c = ei_dst(ei, E, e, i64);
        u32 p = rowptr[c] + atomicAdd(&fillc[c], 1u);
        ent[p] = (u32)r;
    }
}

// g0 = dinv .* h0
__global__ void init_g(const float* __restrict__ h0, const float* __restrict__ dinv,
                       float* __restrict__ g, int N) {
    int i = blockIdx.x * 256 + threadIdx.x;
    if (i < N * 16) g[i] = dinv[i >> 4] * h0[i];
}

// ---------------- APPNP pull step on scaled state g = D^-1/2 h ----------------
// s = g[n] + sum_{r in N(n)} g[r];  h' = 0.9*dinv[n]*s + 0.1*h0[n];  g' = dinv[n]*h'
__global__ __launch_bounds__(256) void prop_kernel(
    const u32* __restrict__ ent, const u32* __restrict__ rowptr,
    const float* __restrict__ dinv, const float* __restrict__ gcur,
    const float* __restrict__ h0, float* __restrict__ gnext,
    void* __restrict__ outp, const u32* __restrict__ flags, int N)
{
    int g = blockIdx.x * 256 + threadIdx.x;
    int n = g >> 4;
    int c = g & 15;
    if (n >= N) return;
    u32 p = rowptr[n], pend = rowptr[n + 1];
    float s = gcur[(size_t)n * 16 + c];          // self loop
    for (; p < pend; ++p) {
        u32 r = ent[p];
        s += gcur[(size_t)r * 16 + c];
    }
    float dn = dinv[n];
    float h = 0.9f * dn * s + 0.1f * h0[(size_t)n * 16 + c];
    if (gnext) {
        gnext[(size_t)n * 16 + c] = dn * h;
    } else {
        if (flags[0]) ((float*)outp)[(size_t)n * 16 + c] = h;
        else          ((u16*)outp)[(size_t)n * 16 + c] = f2bf(h);
    }
}

extern "C" void kernel_launch(void* const* d_in, const int* in_sizes, int n_in,
                              void* d_out, int out_size, void* d_ws, size_t ws_size,
                              hipStream_t stream) {
    const void* x  = d_in[0];
    const int* ei  = (const int*)d_in[1];
    const void* W1 = d_in[2];
    const void* b1 = d_in[3];
    const void* W2 = d_in[4];
    const void* b2 = d_in[5];

    const int N = in_sizes[0] / IN_CH;     // 100000
    const int E = in_sizes[1] / 2;         // 3200000

    float* wf = (float*)d_ws;
    u32*   wu = (u32*)d_ws;

    // workspace layout (4B units), total ~ 33.5 MB
    size_t oH0   = 0;
    size_t oGA   = oH0 + (size_t)N * 16;
    size_t oGB   = oGA + (size_t)N * 16;
    size_t oCNT  = oGB + (size_t)N * 16;
    size_t oFILL = oCNT + N;
    size_t oDINV = oFILL + N;
    size_t oRP   = oDINV + N;
    size_t oPART = ((oRP + N + 1 + 3) & ~(size_t)3);
    size_t oFLG  = oPART + 512;
    size_t oENT  = oFLG + 4;

    detect_kernel<<<1, 64, 0, stream>>>((const u16*)W1, ei, wu + oFLG);
    zero_u32<<<(2 * N + 255) / 256, 256, 0, stream>>>(wu + oCNT, 2 * N);
    mlp_kernel<<<(N + 63) / 64, 256, 0, stream>>>(x, W1, b1, W2, b2, wf + oH0,
                                                  wu + oFLG, N);
    deg_kernel<<<(E + 255) / 256, 256, 0, stream>>>(ei, E, wu + oCNT, wu + oFLG);
    dinv_kernel<<<(N + 255) / 256, 256, 0, stream>>>(wu + oCNT, wf + oDINV, N);
    int NB = (N + 255) / 256;
    scan1<<<NB, 256, 0, stream>>>(wu + oCNT, wu + oPART, N);
    scan2<<<1, 512, 0, stream>>>(wu + oPART, wu + oRP, NB, N);
    scan3<<<NB, 256, 0, stream>>>(wu + oCNT, wu + oPART, wu + oRP, N);
    fill_kernel<<<(E + 255) / 256, 256, 0, stream>>>(ei, E, wu + oRP, wu + oFILL,
                                                     wu + oENT, wu + oFLG);
    init_g<<<(N * 16 + 255) / 256, 256, 0, stream>>>(wf + oH0, wf + oDINV, wf + oGA, N);

    const float* cur = wf + oGA;
    for (int k = 0; k < KSTEPS; ++k) {
        bool last = (k == KSTEPS - 1);
        float* nxt = last ? nullptr : (wf + ((k & 1) ? oGA : oGB));
        prop_kernel<<<(N * 16 + 255) / 256, 256, 0, stream>>>(
            wu + oENT, wu + oRP, wf + oDINV, cur, wf + oH0,
            nxt, last ? d_out : nullptr, wu + oFLG, N);
        if (!last) cur = nxt;
    }
}